// Round 1
// baseline (169.218 us; speedup 1.0000x reference)
//
#include <hip/hip_runtime.h>

// Damped EMA: h[t] = a*x[t] + (1-a)*h[t-1], h[-1]=0, over (B,T,D) fp32.
// Chunked along T with a truncated warm-up window (r^W below fp32 eps).
// B=4, T=4096, D=1024 fixed by the reference.

#define B_ 4
#define T_ 4096
#define D_ 1024
#define CHUNK 128   // timesteps per block
#define DB 256      // floats of D per block = 64 lanes * float4
#define WFIX 16     // unrolled warm-up window (r^16 = 1e-16 for r=0.1)

__global__ __launch_bounds__(64)
void ema_scan_kernel(const float* __restrict__ x,
                     const float* __restrict__ alpha,
                     float* __restrict__ out) {
    const int lane    = threadIdx.x;            // 0..63
    const int dSplits = D_ / DB;                // 4
    const int chunk   = blockIdx.x / dSplits;   // 0..31
    const int dseg    = blockIdx.x % dSplits;
    const int b       = blockIdx.y;
    const int d0      = dseg * DB + lane * 4;
    const int t0      = chunk * CHUNK;

    const float a = alpha[0];
    const float r = 1.0f - a;

    // Window length needed so truncated history < ~1e-12 relative.
    int W;
    if (!(r > 0.0f)) {
        W = 0;                       // alpha >= 1: no history matters
    } else if (r >= 1.0f) {
        W = t0;                      // alpha <= 0: need full history (exact)
    } else {
        W = (int)ceilf(28.0f / (-logf(r)));
        if (W < WFIX) W = WFIX;      // round up to the unrolled fast path
        if (W > t0)   W = t0;
    }

    const float* xp = x   + ((size_t)b * T_ + (size_t)(t0 - W)) * D_ + d0;
    float*       op = out + ((size_t)b * T_ + (size_t)t0) * D_ + d0;

    float4 h = make_float4(0.f, 0.f, 0.f, 0.f);

    // ---- warm-up (discarded outputs) ----
    if (W == WFIX) {
#pragma unroll
        for (int i = 0; i < WFIX; ++i) {
            float4 xv = *(const float4*)xp;
            xp += D_;
            h.x = fmaf(r, h.x, a * xv.x);
            h.y = fmaf(r, h.y, a * xv.y);
            h.z = fmaf(r, h.z, a * xv.z);
            h.w = fmaf(r, h.w, a * xv.w);
        }
    } else {
#pragma unroll 4
        for (int i = 0; i < W; ++i) {
            float4 xv = *(const float4*)xp;
            xp += D_;
            h.x = fmaf(r, h.x, a * xv.x);
            h.y = fmaf(r, h.y, a * xv.y);
            h.z = fmaf(r, h.z, a * xv.z);
            h.w = fmaf(r, h.w, a * xv.w);
        }
    }

    // ---- main: scan CHUNK steps, store each ----
#pragma unroll 8
    for (int i = 0; i < CHUNK; ++i) {
        float4 xv = *(const float4*)xp;
        xp += D_;
        h.x = fmaf(r, h.x, a * xv.x);
        h.y = fmaf(r, h.y, a * xv.y);
        h.z = fmaf(r, h.z, a * xv.z);
        h.w = fmaf(r, h.w, a * xv.w);
        *(float4*)op = h;
        op += D_;
    }
}

extern "C" void kernel_launch(void* const* d_in, const int* in_sizes, int n_in,
                              void* d_out, int out_size, void* d_ws, size_t ws_size,
                              hipStream_t stream) {
    const float* x     = (const float*)d_in[0];
    const float* alpha = (const float*)d_in[1];
    float*       out   = (float*)d_out;

    dim3 grid((T_ / CHUNK) * (D_ / DB), B_);  // 128 x 4 = 512 blocks
    ema_scan_kernel<<<grid, 64, 0, stream>>>(x, alpha, out);
}

// Round 3
// 113.479 us; speedup vs baseline: 1.4912x; 1.4912x over previous
//
#include <hip/hip_runtime.h>

// Damped EMA: h[t] = a*x[t] + (1-a)*h[t-1], h[-1]=0, over (B,T,D) fp32.
// Chunked along T with truncated warm-up window (r^W below fp32 noise).
// Round 3: same as round 2 but with clang ext_vector float4 so
// __builtin_nontemporal_store compiles (HIP float4 is a class type).

#define B_ 4
#define T_ 4096
#define D_ 1024
#define CHUNK 32    // timesteps per block
#define DB 256      // floats of D per block = 64 lanes * float4
#define WFIX 16     // unrolled warm-up window (r^16 = 1e-16 for r=0.1)
#define GRP 8       // loads batched per group in main loop

typedef float v4f __attribute__((ext_vector_type(4)));

__global__ __launch_bounds__(64)
void ema_scan_kernel(const float* __restrict__ x,
                     const float* __restrict__ alpha,
                     float* __restrict__ out) {
    const int lane    = threadIdx.x;            // 0..63
    const int dSplits = D_ / DB;                // 4
    const int chunk   = blockIdx.x / dSplits;   // 0..T_/CHUNK-1
    const int dseg    = blockIdx.x % dSplits;
    const int b       = blockIdx.y;
    const int d0      = dseg * DB + lane * 4;
    const int t0      = chunk * CHUNK;

    const float a = alpha[0];
    const float r = 1.0f - a;

    // Window length so truncated history < ~1e-12 relative.
    int W;
    if (!(r > 0.0f)) {
        W = 0;                       // alpha >= 1: no history matters
    } else if (r >= 1.0f) {
        W = t0;                      // alpha <= 0: need full history (exact)
    } else {
        W = (int)ceilf(28.0f / (-logf(r)));
        if (W < WFIX) W = WFIX;      // round up to the unrolled fast path
        if (W > t0)   W = t0;
    }

    const float* xp = x   + ((size_t)b * T_ + (size_t)(t0 - W)) * D_ + d0;
    float*       op = out + ((size_t)b * T_ + (size_t)t0) * D_ + d0;

    v4f h = (v4f)(0.0f);

    // ---- warm-up (discarded outputs), batched loads ----
    if (W == WFIX) {
        v4f xv[WFIX];
#pragma unroll
        for (int i = 0; i < WFIX; ++i) xv[i] = *(const v4f*)(xp + (size_t)i * D_);
        xp += (size_t)WFIX * D_;
#pragma unroll
        for (int i = 0; i < WFIX; ++i) h = r * h + a * xv[i];
    } else {
        for (int i = 0; i < W; ++i) {
            v4f xv = *(const v4f*)xp;
            xp += D_;
            h = r * h + a * xv;
        }
    }

    // ---- main: scan CHUNK steps in groups of GRP ----
#pragma unroll
    for (int g = 0; g < CHUNK / GRP; ++g) {
        v4f xv[GRP];
#pragma unroll
        for (int j = 0; j < GRP; ++j) xv[j] = *(const v4f*)(xp + (size_t)j * D_);
        xp += (size_t)GRP * D_;
#pragma unroll
        for (int j = 0; j < GRP; ++j) {
            h = r * h + a * xv[j];
            __builtin_nontemporal_store(h, (v4f*)(op + (size_t)j * D_));
        }
        op += (size_t)GRP * D_;
    }
}

extern "C" void kernel_launch(void* const* d_in, const int* in_sizes, int n_in,
                              void* d_out, int out_size, void* d_ws, size_t ws_size,
                              hipStream_t stream) {
    const float* x     = (const float*)d_in[0];
    const float* alpha = (const float*)d_in[1];
    float*       out   = (float*)d_out;

    dim3 grid((T_ / CHUNK) * (D_ / DB), B_);  // 512 x 4 = 2048 blocks
    ema_scan_kernel<<<grid, 64, 0, stream>>>(x, alpha, out);
}